// Round 6
// baseline (57.699 us; speedup 1.0000x reference)
//
#include <hip/hip_runtime.h>
#include <cstddef>

// Problem constants (from reference): B=4, N=4096, D=128, R=4, K=16, O=128
namespace {
constexpr int B_ = 4, N_ = 4096, D_ = 128, R_ = 4, K_ = 16, O_ = 128;
constexpr int NP1 = N_ + 1;            // padded table rows (row 0 = zeros)
constexpr int KK = (R_ + 1) * D_;      // 640 stacked-K (4 relations + self)
constexpr int KR = R_ * D_;            // 512 relation-K
}

typedef __bf16 bf16x8 __attribute__((ext_vector_type(8)));
typedef __bf16 bf16x4 __attribute__((ext_vector_type(4)));
typedef __bf16 bf16x2 __attribute__((ext_vector_type(2)));
typedef float  f32x4v __attribute__((ext_vector_type(4)));
typedef float  f32x2v __attribute__((ext_vector_type(2)));
using u32 = unsigned int;

// ---- prep (fused): bf16 padded table + transposed bf16 W^T ----
// ptab[B][NP1][D]: row 0 zeros, row i+1 = node i features.
// wt[O][KK]: wt[o][kk] = stackedW[kk][o]; relation rows pre-scaled by 1/16
// (exact pow-2) so the gather kernel can store raw K-sums.
__global__ __launch_bounds__(256)
void prep_all(const float* __restrict__ nf, const float* __restrict__ relk,
              const float* __restrict__ selfk,
              __bf16* __restrict__ ptab, __bf16* __restrict__ wt) {
    int t = blockIdx.x * 256 + threadIdx.x;
    const int total_tab = B_ * NP1 * (D_ / 4);          // bf16x4 chunks
    if (t < total_tab) {
        const int b   = t / (NP1 * 32);
        const int rem = t % (NP1 * 32);
        const int row = rem >> 5;
        const int q   = rem & 31;
        bf16x4 res;
        if (row == 0) {
            res[0] = (__bf16)0.f; res[1] = (__bf16)0.f;
            res[2] = (__bf16)0.f; res[3] = (__bf16)0.f;
        } else {
            const float4 v = *(const float4*)(nf + ((size_t)b * N_ + (row - 1)) * D_ + q * 4);
            res[0] = (__bf16)v.x; res[1] = (__bf16)v.y;
            res[2] = (__bf16)v.z; res[3] = (__bf16)v.w;
        }
        *(bf16x4*)(ptab + ((size_t)b * NP1 + row) * D_ + q * 4) = res;
        return;
    }
    t -= total_tab;
    if (t < O_ * (KK / 4)) {
        const int o   = t / (KK / 4);
        const int kk  = (t % (KK / 4)) * 4;
        bf16x4 res;
        #pragma unroll
        for (int i = 0; i < 4; ++i) {
            const int kki = kk + i;
            const float w = (kki < KR) ? relk[(size_t)kki * O_ + o] * 0.0625f
                                       : selfk[(size_t)(kki - KR) * O_ + o];
            res[i] = (__bf16)w;
        }
        *(bf16x4*)(wt + (size_t)o * KK + kk) = res;
    }
}

// ---- gather: pure streaming K-sum, no LDS, 32 waves/CU ----
// 4096 blocks x 4 waves; wave = (batch via XCD affinity, relation, 4 nodes).
// aggw[b*N+n][KR]: kk = r*128+d, bf16 K-sums.
__global__ __launch_bounds__(256, 8)
void gcn_gather(const __bf16* __restrict__ ptab, const int* __restrict__ nbr,
                __bf16* __restrict__ aggw)
{
    const int hw  = blockIdx.x;
    const int xcd = hw & 7;
    const int b   = xcd >> 1;                    // XCD pair {2b,2b+1} -> batch b
    const int lb  = ((hw >> 3) << 1) | (xcd & 1);  // 0..1023 within batch
    const int wv  = threadIdx.x >> 6;            // relation 0..3
    const int l   = threadIdx.x & 63;            // bf16 elements 2l, 2l+1
    const int n0  = lb * 4;

    const __bf16* __restrict__ tb = ptab + (size_t)b * NP1 * D_;
    const int ioff = __builtin_amdgcn_readfirstlane((((b * R_ + wv) * N_) + n0) * K_);
    const int* __restrict__ ib = nbr + ioff;

    #pragma unroll 2
    for (int n = 0; n < 4; ++n) {
        int sidx[K_];
        #pragma unroll
        for (int k = 0; k < K_; ++k) sidx[k] = ib[n * K_ + k];

        f32x2v a0 = {0.f, 0.f}, a1 = {0.f, 0.f}, a2 = {0.f, 0.f}, a3 = {0.f, 0.f};
        #pragma unroll
        for (int k = 0; k < K_; ++k) {
            const u32 u = *((const u32*)(tb + (size_t)sidx[k] * D_) + l);
            f32x2v v;
            v.x = __uint_as_float(u << 16);
            v.y = __uint_as_float(u & 0xffff0000u);
            switch (k & 3) {
                case 0:  a0 += v; break;
                case 1:  a1 += v; break;
                case 2:  a2 += v; break;
                default: a3 += v; break;
            }
        }
        const f32x2v s = (a0 + a1) + (a2 + a3);    // raw sum; 1/16 folded into W
        bf16x2 res;
        res[0] = (__bf16)s.x;
        res[1] = (__bf16)s.y;
        *(bf16x2*)(aggw + ((size_t)(b * N_ + n0 + n)) * KR + wv * D_ + l * 2) = res;
    }
}

// ---- GEMM: out[16384][128] = relu(agg @ Wrel + self @ Wself + bias) ----
// 512 blocks x 8 waves; block = 32 nodes, wave = 16-col tile x 2 M-subtiles.
// A read from global (L2-resident, 8x L1 reuse across waves); self K-chunk
// read directly from ptab. No LDS.
__global__ __launch_bounds__(512, 8)
void gcn_gemm(const __bf16* __restrict__ aggw, const __bf16* __restrict__ ptab,
              const __bf16* __restrict__ wt, const float* __restrict__ bias,
              float* __restrict__ out)
{
    const int hw = blockIdx.x;                   // 512
    const int b  = hw >> 7;                      // 128 blocks per batch
    const int n0 = (hw & 127) * 32;
    const int wv = threadIdx.x >> 6;             // col tile 0..7
    const int l  = threadIdx.x & 63;
    const int lr = l & 15;                       // A row / B col / C col
    const int lk = l >> 4;                       // k-group

    const __bf16* __restrict__ wr  = wt + (size_t)(wv * 16 + lr) * KK + lk * 8;
    const __bf16* __restrict__ ar0 = aggw + (size_t)(b * N_ + n0 + lr) * KR + lk * 8;
    const __bf16* __restrict__ ar1 = ar0 + 16 * KR;
    const __bf16* __restrict__ sp0 = ptab + ((size_t)b * NP1 + n0 + lr + 1) * D_ + lk * 8;
    const __bf16* __restrict__ sp1 = sp0 + 16 * D_;

    f32x4v acc0 = {0.f, 0.f, 0.f, 0.f};
    f32x4v acc1 = {0.f, 0.f, 0.f, 0.f};
    #pragma unroll 4
    for (int k0 = 0; k0 < KR; k0 += 32) {
        const bf16x8 w  = *(const bf16x8*)(wr + k0);
        const bf16x8 a0 = *(const bf16x8*)(ar0 + k0);
        const bf16x8 a1 = *(const bf16x8*)(ar1 + k0);
        acc0 = __builtin_amdgcn_mfma_f32_16x16x32_bf16(a0, w, acc0, 0, 0, 0);
        acc1 = __builtin_amdgcn_mfma_f32_16x16x32_bf16(a1, w, acc1, 0, 0, 0);
    }
    #pragma unroll
    for (int k0 = 0; k0 < D_; k0 += 32) {
        const bf16x8 w  = *(const bf16x8*)(wr + KR + k0);
        const bf16x8 a0 = *(const bf16x8*)(sp0 + k0);
        const bf16x8 a1 = *(const bf16x8*)(sp1 + k0);
        acc0 = __builtin_amdgcn_mfma_f32_16x16x32_bf16(a0, w, acc0, 0, 0, 0);
        acc1 = __builtin_amdgcn_mfma_f32_16x16x32_bf16(a1, w, acc1, 0, 0, 0);
    }

    const float bv = bias[wv * 16 + lr];
    #pragma unroll
    for (int j = 0; j < 4; ++j) {
        const int row0 = n0 + lk * 4 + j;
        out[((size_t)b * N_ + row0) * O_ + wv * 16 + lr]      = fmaxf(acc0[j] + bv, 0.f);
        out[((size_t)b * N_ + row0 + 16) * O_ + wv * 16 + lr] = fmaxf(acc1[j] + bv, 0.f);
    }
}

extern "C" void kernel_launch(void* const* d_in, const int* in_sizes, int n_in,
                              void* d_out, int out_size, void* d_ws, size_t ws_size,
                              hipStream_t stream) {
    const float* nf    = (const float*)d_in[0];  // node_features  [B,N,D] f32
    const int*   nbr   = (const int*)  d_in[1];  // neighbor_indices [B,R,N,K] i32
    const float* relk  = (const float*)d_in[2];  // relation_kernels [R,D,O] f32
    const float* selfk = (const float*)d_in[3];  // self_kernel [D,O] f32
    const float* bias  = (const float*)d_in[4];  // bias [O] f32
    float* outp = (float*)d_out;                 // [B,N,O] f32

    // ws layout: ptab | wt | aggw
    __bf16* ptab = (__bf16*)d_ws;                                   // 4,195,328 B
    __bf16* wtp  = ptab + (size_t)B_ * NP1 * D_;                    // 163,840 B
    __bf16* aggw = wtp + (size_t)O_ * KK;                           // 16,777,216 B

    {
        const int total = B_ * NP1 * (D_ / 4) + O_ * (KK / 4);
        prep_all<<<(total + 255) / 256, 256, 0, stream>>>(nf, relk, selfk, ptab, wtp);
    }
    gcn_gather<<<4096, 256, 0, stream>>>(ptab, nbr, aggw);
    gcn_gemm<<<512, 512, 0, stream>>>(aggw, ptab, wtp, bias, outp);
}